// Round 1
// baseline (316.403 us; speedup 1.0000x reference)
//
#include <hip/hip_runtime.h>

#define SEQ_L 1024
#define BATCH_N 512
#define NTAG 48

__device__ inline float readlane_f(float v, int lane) {
    return __int_as_float(__builtin_amdgcn_readlane(__float_as_int(v), lane));
}

__device__ inline float wave_sum_f(float v) {
    #pragma unroll
    for (int off = 32; off > 0; off >>= 1) v += __shfl_xor(v, off, 64);
    return v;
}

__device__ inline int wave_sum_i(int v) {
    #pragma unroll
    for (int off = 32; off > 0; off >>= 1) v += __shfl_xor(v, off, 64);
    return v;
}

// Prefetch 8 emission values + masks for steps i = 1 + blk*8 + k  (k=0..7)
__device__ inline void prefetch8(float (&eb)[8], int (&mb)[8], int blk, int b,
                                 bool act, int lane,
                                 const float* __restrict__ emissions,
                                 const int* __restrict__ mask) {
    #pragma unroll
    for (int k = 0; k < 8; ++k) {
        int i = 1 + blk * 8 + k;
        bool ok = (blk < 128) && (i < SEQ_L);
        eb[k] = (act && ok) ? emissions[((size_t)i * BATCH_N + b) * NTAG + lane] : 0.0f;
        mb[k] = ok ? mask[i * BATCH_N + b] : 0;
    }
}

// Run 8 scan steps (scaled-prob domain) + one renormalization.
__device__ inline void step8(float& p, float& C,
                             const float (&eb)[8], const int (&mb)[8],
                             const float (&Ecol)[NTAG]) {
    #pragma unroll
    for (int k = 0; k < 8; ++k) {
        float a0 = 0.0f, a1 = 0.0f, a2 = 0.0f, a3 = 0.0f;
        #pragma unroll
        for (int t = 0; t < NTAG; t += 4) {
            a0 = fmaf(readlane_f(p, t + 0), Ecol[t + 0], a0);
            a1 = fmaf(readlane_f(p, t + 1), Ecol[t + 1], a1);
            a2 = fmaf(readlane_f(p, t + 2), Ecol[t + 2], a2);
            a3 = fmaf(readlane_f(p, t + 3), Ecol[t + 3], a3);
        }
        float nxt = ((a0 + a1) + (a2 + a3)) * __expf(eb[k]);
        p = mb[k] ? nxt : p;   // masked step keeps alpha
    }
    // renormalize: divide by sum, fold into log-offset C
    float s = wave_sum_f(p);
    C += __logf(s);
    p *= (1.0f / s);
}

__global__ __launch_bounds__(64) void crf_fwd_kernel(
    const float* __restrict__ emissions,
    const float* __restrict__ start_t,
    const float* __restrict__ end_t,
    const float* __restrict__ trans,
    const int*   __restrict__ tags,
    const int*   __restrict__ mask,
    float*       __restrict__ out_per_batch) {
    const int b = blockIdx.x;
    const int lane = threadIdx.x;
    const bool act = lane < NTAG;

    // ---- Preload exp(transitions) column for this lane: Ecol[t] = exp(trans[t][lane])
    float Ecol[NTAG];
    #pragma unroll
    for (int t = 0; t < NTAG; ++t)
        Ecol[t] = act ? __expf(trans[t * NTAG + lane]) : 0.0f;

    // ---- init: p = exp(start + emissions[0]), C = 0
    float p = act ? __expf(start_t[lane] + emissions[(size_t)b * NTAG + lane]) : 0.0f;
    float C = 0.0f;

    // ---- scan over i = 1..1023 in 128 blocks of 8 (last block partially masked off)
    float eA[8], eB[8];
    int   mA[8], mB[8];
    prefetch8(eA, mA, 0, b, act, lane, emissions, mask);
    prefetch8(eB, mB, 1, b, act, lane, emissions, mask);
    for (int blk = 0; blk < 128; blk += 2) {
        step8(p, C, eA, mA, Ecol);
        prefetch8(eA, mA, blk + 2, b, act, lane, emissions, mask);
        step8(p, C, eB, mB, Ecol);
        prefetch8(eB, mB, blk + 3, b, act, lane, emissions, mask);
    }

    // ---- log_z = C + log(sum_t p[t] * exp(end[t]))
    float zterm = act ? p * __expf(end_t[lane]) : 0.0f;
    float zs = wave_sum_f(zterm);
    float log_z = C + __logf(zs);

    // ---- numerator: all 64 lanes, 16 timesteps each
    float numpart = 0.0f;
    int cnt = 0;
    #pragma unroll 4
    for (int j = 0; j < SEQ_L / 64; ++j) {
        int i = j * 64 + lane;
        int tag_i = tags[(size_t)i * BATCH_N + b];
        int m = mask[i * BATCH_N + b];
        cnt += (m != 0);
        if (i == 0) {
            numpart += start_t[tag_i] + emissions[(size_t)b * NTAG + tag_i];
        } else if (m) {
            int tag_p = tags[(size_t)(i - 1) * BATCH_N + b];
            numpart += trans[tag_p * NTAG + tag_i] +
                       emissions[((size_t)i * BATCH_N + b) * NTAG + tag_i];
        }
    }
    float num = wave_sum_f(numpart);
    int seq_len = wave_sum_i(cnt);
    int last_tag = tags[(size_t)(seq_len - 1) * BATCH_N + b];
    num += end_t[last_tag];

    if (lane == 0) out_per_batch[b] = log_z - num;   // = -llh[b]
}

__global__ __launch_bounds__(512) void reduce512_kernel(
    const float* __restrict__ v, float* __restrict__ out) {
    float x = v[threadIdx.x];
    x = wave_sum_f(x);
    __shared__ float ws[8];
    int w = threadIdx.x >> 6;
    if ((threadIdx.x & 63) == 0) ws[w] = x;
    __syncthreads();
    if (threadIdx.x == 0) {
        float t = 0.0f;
        #pragma unroll
        for (int k = 0; k < 8; ++k) t += ws[k];
        *out = t;   // sum_b (log_z - num) = -sum(llh)
    }
}

extern "C" void kernel_launch(void* const* d_in, const int* in_sizes, int n_in,
                              void* d_out, int out_size, void* d_ws, size_t ws_size,
                              hipStream_t stream) {
    const float* emissions = (const float*)d_in[0];
    const float* start_t   = (const float*)d_in[1];
    const float* end_t     = (const float*)d_in[2];
    const float* trans     = (const float*)d_in[3];
    const int*   tags      = (const int*)d_in[4];
    const int*   mask      = (const int*)d_in[5];
    float* per_batch = (float*)d_ws;

    crf_fwd_kernel<<<BATCH_N, 64, 0, stream>>>(emissions, start_t, end_t, trans,
                                               tags, mask, per_batch);
    reduce512_kernel<<<1, 512, 0, stream>>>(per_batch, (float*)d_out);
}